// Round 1
// baseline (14.946 us; speedup 1.0000x reference)
//
#include <hip/hip_runtime.h>
#include <hip/hip_bf16.h>

// AxonalConnections: out[b,t] = sum_s adj[t,s] * ((1.5*E[s]-0.5)*spikes[b,s])
// adj is conv-structured: nonzeros only at s = (ti-1+ki)*128 + (tj-1+kj),
// ki,kj in [0,3). H=W=128, B=32. Exploit sparsity: gather 9 weights/target.

#define H 128
#define W 128
#define S (H * W)          // 16384
#define B 32
#define BATCH_PER_Y 4      // gridDim.y = B / BATCH_PER_Y = 8

__global__ __launch_bounds__(256) void AxonalConnections_22608707846341_kernel(
    const float* __restrict__ spikes,   // [B, S]
    const float* __restrict__ E,        // [S]
    const float* __restrict__ adj,      // [S, S] dense, conv-sparse
    float* __restrict__ out)            // [B, S]
{
    const int t  = blockIdx.x * blockDim.x + threadIdx.x;  // target index 0..S-1
    const int ti = t >> 7;          // t / W
    const int tj = t & (W - 1);     // t % W

    // Gather the 9 structurally-nonzero weights for this target row,
    // fold in the E-modulation of the corresponding source.
    float w[9];
    int   src[9];
    const size_t rowbase = (size_t)t * (size_t)S;
#pragma unroll
    for (int ki = 0; ki < 3; ++ki) {
#pragma unroll
        for (int kj = 0; kj < 3; ++kj) {
            const int k  = ki * 3 + kj;
            const int si = ti - 1 + ki;
            const int sj = tj - 1 + kj;
            const bool valid = (si >= 0) & (si < H) & (sj >= 0) & (sj < W);
            const int s = valid ? (si * W + sj) : 0;
            src[k] = s;
            float wk = valid ? adj[rowbase + (size_t)s] : 0.0f;
            // mod factor: E=1 -> +1.0, E=0 -> -0.5  ==  1.5*E - 0.5
            w[k] = wk * (1.5f * E[s] - 0.5f);
        }
    }

    // Loop over this y-group's batch slice: 9 FMAs per output element.
    const int b0 = blockIdx.y * BATCH_PER_Y;
#pragma unroll
    for (int bb = 0; bb < BATCH_PER_Y; ++bb) {
        const int b = b0 + bb;
        const float* __restrict__ sp = spikes + (size_t)b * S;
        float acc = 0.0f;
#pragma unroll
        for (int k = 0; k < 9; ++k)
            acc = fmaf(w[k], sp[src[k]], acc);
        out[(size_t)b * S + t] = acc;
    }
}

extern "C" void kernel_launch(void* const* d_in, const int* in_sizes, int n_in,
                              void* d_out, int out_size, void* d_ws, size_t ws_size,
                              hipStream_t stream) {
    const float* spikes = (const float*)d_in[0];   // [32,128,128] f32
    const float* E      = (const float*)d_in[1];   // [128,128]    f32
    const float* adj    = (const float*)d_in[2];   // [16384,16384] f32
    float* out          = (float*)d_out;           // [32,128,128] f32

    dim3 block(256);
    dim3 grid(S / 256, B / BATCH_PER_Y);           // (64, 8)
    AxonalConnections_22608707846341_kernel<<<grid, block, 0, stream>>>(
        spikes, E, adj, out);
}

// Round 2
// 14.870 us; speedup vs baseline: 1.0051x; 1.0051x over previous
//
#include <hip/hip_runtime.h>
#include <hip/hip_bf16.h>

// AxonalConnections: out[b,t] = sum_s adj[t,s] * ((1.5*E[s]-0.5)*spikes[b,s])
// adj is conv-structured (3x3 stencil, H=W=128, PAD=1): only 9 nonzeros per
// target row. Gather 9 weights/target, fuse E-modulation, 9 FMAs/batch-elem.
//
// R1: 14.9us with BATCH_PER_Y=4 (512 blocks). Latency-bound on the
// uncoalesced adj gather (lanes' rows are 64KB apart -> 64 lines/load-instr).
// R2: BATCH_PER_Y=2 -> 1024 blocks, 16 waves/CU, shorter serial tail; adj
// redundancy (16x) is L2-absorbed (unique ~3MB < 4MB/XCD L2).

#define H 128
#define W 128
#define S (H * W)          // 16384
#define B 32
#define BATCH_PER_Y 2      // gridDim.y = B / BATCH_PER_Y = 16

__global__ __launch_bounds__(256) void AxonalConnections_22608707846341_kernel(
    const float* __restrict__ spikes,   // [B, S]
    const float* __restrict__ E,        // [S]
    const float* __restrict__ adj,      // [S, S] dense, conv-sparse
    float* __restrict__ out)            // [B, S]
{
    const int t  = blockIdx.x * blockDim.x + threadIdx.x;  // target 0..S-1
    const int ti = t >> 7;          // t / W
    const int tj = t & (W - 1);     // t % W

    const size_t rowbase = (size_t)t * (size_t)S;

    // Precompute validity + source indices (pure VALU, no loads).
    int   src[9];
    bool  valid[9];
#pragma unroll
    for (int ki = 0; ki < 3; ++ki) {
#pragma unroll
        for (int kj = 0; kj < 3; ++kj) {
            const int k  = ki * 3 + kj;
            const int si = ti - 1 + ki;
            const int sj = tj - 1 + kj;
            valid[k] = (si >= 0) & (si < H) & (sj >= 0) & (sj < W);
            src[k]   = valid[k] ? (si * W + sj) : 0;
        }
    }

    // Issue all 9 scattered adjacency loads back-to-back (independent, max
    // outstanding vmcnt), then the 9 E loads (L2-hot, coalesced-ish).
    float wraw[9];
#pragma unroll
    for (int k = 0; k < 9; ++k)
        wraw[k] = adj[rowbase + (size_t)src[k]];

    float w[9];
#pragma unroll
    for (int k = 0; k < 9; ++k) {
        // mod factor: E=1 -> +1.0, E=0 -> -0.5  ==  1.5*E - 0.5
        const float f = 1.5f * E[src[k]] - 0.5f;
        w[k] = valid[k] ? (wraw[k] * f) : 0.0f;
    }

    // Batch slice: 9 FMAs per output element, coalesced spike loads.
    const int b0 = blockIdx.y * BATCH_PER_Y;
#pragma unroll
    for (int bb = 0; bb < BATCH_PER_Y; ++bb) {
        const int b = b0 + bb;
        const float* __restrict__ sp = spikes + (size_t)b * S;
        float acc = 0.0f;
#pragma unroll
        for (int k = 0; k < 9; ++k)
            acc = fmaf(w[k], sp[src[k]], acc);
        out[(size_t)b * S + t] = acc;
    }
}

extern "C" void kernel_launch(void* const* d_in, const int* in_sizes, int n_in,
                              void* d_out, int out_size, void* d_ws, size_t ws_size,
                              hipStream_t stream) {
    const float* spikes = (const float*)d_in[0];   // [32,128,128] f32
    const float* E      = (const float*)d_in[1];   // [128,128]    f32
    const float* adj    = (const float*)d_in[2];   // [16384,16384] f32
    float* out          = (float*)d_out;           // [32,128,128] f32

    dim3 block(256);
    dim3 grid(S / 256, B / BATCH_PER_Y);           // (64, 16)
    AxonalConnections_22608707846341_kernel<<<grid, block, 0, stream>>>(
        spikes, E, adj, out);
}

// Round 3
// 12.576 us; speedup vs baseline: 1.1885x; 1.1825x over previous
//
#include <hip/hip_runtime.h>
#include <hip/hip_bf16.h>

// AxonalConnections: out[b,t] = sum_s adj[t,s] * ((1.5*E[s]-0.5)*spikes[b,s])
// adj is conv-structured (3x3 stencil, H=W=128, PAD=1): 9 nonzeros/target row.
//
// R1/R2 (single fused kernel, per-thread 9-tap gather): 14.9us, insensitive
// to TLP. Diagnosis: gather transaction floor — 9 loads/thread x 64 lines/
// load-instr (rows 64KB apart), repeated per batch-group (16x redundancy).
//
// R3: two-phase through d_ws.
//   A) compact: thread per (t,k) tap -> one load each, lanes 0..8 cover one
//      row's 3 contiguous clusters (~24 lines/instr vs 64), adj lines read
//      exactly once. Fold E-modulation + validity. Write wT[k][t] transposed.
//   B) apply: thread per target; 9 coalesced wT loads, 9 coalesced spike
//      window loads per batch, coalesced store. All L2/L3-hot.

#define H 128
#define W 128
#define S (H * W)          // 16384
#define B 32
#define BPY 2              // kernel B: batches per y-block -> grid.y = 16

__global__ __launch_bounds__(256) void axc_compact_kernel(
    const float* __restrict__ E,        // [S]
    const float* __restrict__ adj,      // [S, S] dense, conv-sparse
    float* __restrict__ wT)             // [9, S] compacted, E-folded
{
    const int u = blockIdx.x * blockDim.x + threadIdx.x;  // 0 .. 9*S-1
    const int t = u / 9;
    const int k = u - t * 9;
    const int ti = t >> 7;
    const int tj = t & (W - 1);
    const int ki = k / 3;
    const int kj = k - ki * 3;
    const int si = ti - 1 + ki;
    const int sj = tj - 1 + kj;
    const bool valid = (si >= 0) & (si < H) & (sj >= 0) & (sj < W);
    const int s = valid ? (si * W + sj) : 0;

    float v = 0.0f;
    if (valid) {
        const float a = adj[(size_t)t * S + (size_t)s];
        v = a * (1.5f * E[s] - 0.5f);   // E=1 -> +1.0, E=0 -> -0.5
    }
    wT[k * S + t] = v;
}

__global__ __launch_bounds__(256) void axc_apply_kernel(
    const float* __restrict__ spikes,   // [B, S]
    const float* __restrict__ wT,       // [9, S]
    float* __restrict__ out)            // [B, S]
{
    const int t  = blockIdx.x * blockDim.x + threadIdx.x;
    const int ti = t >> 7;
    const int tj = t & (W - 1);

    // 9 fully-coalesced weight loads (lane-consecutive t -> contiguous).
    float w[9];
#pragma unroll
    for (int k = 0; k < 9; ++k)
        w[k] = wT[k * S + t];

    // Source indices (invalid taps have w==0, so dummy index 0 is safe).
    int src[9];
#pragma unroll
    for (int ki = 0; ki < 3; ++ki) {
#pragma unroll
        for (int kj = 0; kj < 3; ++kj) {
            const int k  = ki * 3 + kj;
            const int si = ti - 1 + ki;
            const int sj = tj - 1 + kj;
            const bool valid = (si >= 0) & (si < H) & (sj >= 0) & (sj < W);
            src[k] = valid ? (si * W + sj) : 0;
        }
    }

    const int b0 = blockIdx.y * BPY;
#pragma unroll
    for (int bb = 0; bb < BPY; ++bb) {
        const int b = b0 + bb;
        const float* __restrict__ sp = spikes + (size_t)b * S;
        float acc = 0.0f;
#pragma unroll
        for (int k = 0; k < 9; ++k)
            acc = fmaf(w[k], sp[src[k]], acc);
        out[(size_t)b * S + t] = acc;
    }
}

extern "C" void kernel_launch(void* const* d_in, const int* in_sizes, int n_in,
                              void* d_out, int out_size, void* d_ws, size_t ws_size,
                              hipStream_t stream) {
    const float* spikes = (const float*)d_in[0];   // [32,128,128] f32
    const float* E      = (const float*)d_in[1];   // [128,128]    f32
    const float* adj    = (const float*)d_in[2];   // [16384,16384] f32
    float* out          = (float*)d_out;           // [32,128,128] f32
    float* wT           = (float*)d_ws;            // [9,16384] f32 = 576KB

    // Phase A: compact adjacency (read once) + fold E.
    axc_compact_kernel<<<dim3((9 * S) / 256), dim3(256), 0, stream>>>(E, adj, wT);

    // Phase B: apply stencil to all batches.
    axc_apply_kernel<<<dim3(S / 256, B / BPY), dim3(256), 0, stream>>>(spikes, wT, out);
}

// Round 4
// 9.863 us; speedup vs baseline: 1.5155x; 1.2751x over previous
//
#include <hip/hip_runtime.h>
#include <hip/hip_bf16.h>

// AxonalConnections: out[b,t] = sum_s adj[t,s] * ((1.5*E[s]-0.5)*spikes[b,s])
// adj is conv-structured (3x3 stencil, H=W=128, PAD=1): 9 nonzeros/target row.
//
// R1/R2 (thread-per-target 9-tap gather): 14.9us. Gather = 64 lines/load-instr.
// R3 (two-phase compact->apply via d_ws): 12.6us. Clustered gather works, but
//    pays 2 serialized dispatches + wT round-trip.
// R4: single fused kernel. Per-block tap-parallel clustered gather into LDS
//    (consecutive threads cover taps of the same adj row -> ~24 lines/instr,
//    adj lines fetched ~2x total), then per-wave batch apply with coalesced
//    spike/out access. Grid (256,2)=512 blocks, one dispatch.

#define H 128
#define W 128
#define S (H * W)          // 16384
#define B 32
#define TPB 256
#define TGT_PER_BLK 64     // targets per block (one row-half: ti fixed)
#define NTAPS (TGT_PER_BLK * 9)   // 576
#define YGRID 2            // batch groups; 16 batches per block

__global__ __launch_bounds__(TPB) void AxonalConnections_22608707846341_kernel(
    const float* __restrict__ spikes,   // [B, S]
    const float* __restrict__ E,        // [S]
    const float* __restrict__ adj,      // [S, S] dense, conv-sparse
    float* __restrict__ out)            // [B, S]
{
    __shared__ float wsm[9][TGT_PER_BLK];   // 2.25 KB

    const int tid = threadIdx.x;
    const int t0  = blockIdx.x * TGT_PER_BLK;

    // ---- Phase 1: clustered tap gather into LDS ----
    // u = tL*9 + k; consecutive threads walk taps of the same target row,
    // whose 3 clusters are contiguous in adj -> ~24 cache lines per wave-load.
#pragma unroll
    for (int iter = 0; iter < 3; ++iter) {
        const int u = iter * TPB + tid;
        if (u < NTAPS) {
            const int tL = u / 9;            // magic-mul
            const int k  = u - tL * 9;
            const int t  = t0 + tL;
            const int ti = t >> 7;
            const int tj = t & (W - 1);
            const int ki = k / 3;
            const int kj = k - ki * 3;
            const int si = ti - 1 + ki;
            const int sj = tj - 1 + kj;
            const bool valid = (si >= 0) & (si < H) & (sj >= 0) & (sj < W);
            const int s = valid ? (si * W + sj) : 0;
            float v = 0.0f;
            if (valid) {
                // E=1 -> +1.0, E=0 -> -0.5  ==  1.5*E - 0.5
                v = adj[(size_t)t * S + (size_t)s] * (1.5f * E[s] - 0.5f);
            }
            wsm[k][tL] = v;
        }
    }
    __syncthreads();

    // ---- Phase 2: apply. wave = one batch subgroup, lanes = 64 targets ----
    const int tL = tid & 63;
    const int bg = tid >> 6;                 // 0..3
    const int t  = t0 + tL;
    const int ti = t >> 7;
    const int tj = t & (W - 1);

    float w[9];
#pragma unroll
    for (int k = 0; k < 9; ++k)
        w[k] = wsm[k][tL];                   // stride-1 across lanes, 2-way free

    int src[9];
#pragma unroll
    for (int ki = 0; ki < 3; ++ki) {
#pragma unroll
        for (int kj = 0; kj < 3; ++kj) {
            const int k  = ki * 3 + kj;
            const int si = ti - 1 + ki;
            const int sj = tj - 1 + kj;
            const bool valid = (si >= 0) & (si < H) & (sj >= 0) & (sj < W);
            src[k] = valid ? (si * W + sj) : 0;   // w[k]==0 when invalid
        }
    }

    // 16 batches per block: 4 waves x 4 batches each.
    const int bbase = blockIdx.y * (B / YGRID) + bg * (B / YGRID / 4);
#pragma unroll
    for (int bb = 0; bb < (B / YGRID / 4); ++bb) {
        const int b = bbase + bb;
        const float* __restrict__ sp = spikes + (size_t)b * S;
        float acc = 0.0f;
#pragma unroll
        for (int k = 0; k < 9; ++k)
            acc = fmaf(w[k], sp[src[k]], acc);
        out[(size_t)b * S + t] = acc;
    }
}

extern "C" void kernel_launch(void* const* d_in, const int* in_sizes, int n_in,
                              void* d_out, int out_size, void* d_ws, size_t ws_size,
                              hipStream_t stream) {
    const float* spikes = (const float*)d_in[0];   // [32,128,128] f32
    const float* E      = (const float*)d_in[1];   // [128,128]    f32
    const float* adj    = (const float*)d_in[2];   // [16384,16384] f32
    float* out          = (float*)d_out;           // [32,128,128] f32

    dim3 block(TPB);
    dim3 grid(S / TGT_PER_BLK, YGRID);             // (256, 2) = 512 blocks
    AxonalConnections_22608707846341_kernel<<<grid, block, 0, stream>>>(
        spikes, E, adj, out);
}

// Round 5
// 9.853 us; speedup vs baseline: 1.5169x; 1.0009x over previous
//
#include <hip/hip_runtime.h>
#include <hip/hip_bf16.h>

// AxonalConnections: out[b,t] = sum_s adj[t,s] * ((1.5*E[s]-0.5)*spikes[b,s])
// adj is conv-structured (3x3 stencil, H=W=128, PAD=1): 9 nonzeros/target row.
//
// R1/R2 thread-per-target gather: 14.9us (64 lines/load-instr, batch-redundant).
// R3 two-phase via d_ws: 12.6us (clustered gather good; dispatch serialization bad).
// R4 fused LDS gather + apply, (256,2) grid: 9.86us.
// R5: (a) pre-issue spike loads BEFORE the barrier so adj-gather and
//     spike-gather latencies overlap (single combined drain at s_barrier);
//     (b) YGRID=4 -> 1024 blocks (4/CU), 2 batches/wave;
//     (c) flat wsm[576]: conflict-free LDS writes (R4's [9][64] layout was a
//     ~9-way write conflict), stride-9 reads are 2-lanes/bank = free.

#define H 128
#define W 128
#define S (H * W)          // 16384
#define B 32
#define TPB 256
#define TGT_PER_BLK 64
#define NTAPS (TGT_PER_BLK * 9)   // 576
#define YGRID 4
#define BPB (B / YGRID)    // 8 batches per block
#define BPW (BPB / 4)      // 2 batches per wave

__global__ __launch_bounds__(TPB) void AxonalConnections_22608707846341_kernel(
    const float* __restrict__ spikes,   // [B, S]
    const float* __restrict__ E,        // [S]
    const float* __restrict__ adj,      // [S, S] dense, conv-sparse
    float* __restrict__ out)            // [B, S]
{
    __shared__ float wsm[NTAPS];        // flat: write at u (conflict-free)

    const int tid = threadIdx.x;
    const int t0  = blockIdx.x * TGT_PER_BLK;

    // ---- Phase 1: clustered tap gather into LDS ----
    // u = tL*9 + k; consecutive threads walk taps of the same target row
    // (3 contiguous clusters in adj) -> ~24 cache lines per wave-load.
#pragma unroll
    for (int iter = 0; iter < 3; ++iter) {
        const int u = iter * TPB + tid;
        if (u < NTAPS) {
            const int tL = u / 9;
            const int k  = u - tL * 9;
            const int t  = t0 + tL;
            const int ti = t >> 7;
            const int tj = t & (W - 1);
            const int ki = k / 3;
            const int kj = k - ki * 3;
            const int si = ti - 1 + ki;
            const int sj = tj - 1 + kj;
            const bool valid = (si >= 0) & (si < H) & (sj >= 0) & (sj < W);
            const int s = valid ? (si * W + sj) : 0;
            float v = 0.0f;
            if (valid) {
                // E=1 -> +1.0, E=0 -> -0.5  ==  1.5*E - 0.5
                v = adj[(size_t)t * S + (size_t)s] * (1.5f * E[s] - 0.5f);
            }
            wsm[u] = v;                 // consecutive across threads
        }
    }

    // ---- Phase 2 setup: src indices + PRE-ISSUE spike loads (independent of
    // wsm) so their latency overlaps the adj gather drain at the barrier. ----
    const int tL = tid & 63;
    const int bg = tid >> 6;            // wave id 0..3
    const int t  = t0 + tL;
    const int ti = t >> 7;
    const int tj = t & (W - 1);

    int src[9];
#pragma unroll
    for (int ki = 0; ki < 3; ++ki) {
#pragma unroll
        for (int kj = 0; kj < 3; ++kj) {
            const int k  = ki * 3 + kj;
            const int si = ti - 1 + ki;
            const int sj = tj - 1 + kj;
            const bool valid = (si >= 0) & (si < H) & (sj >= 0) & (sj < W);
            src[k] = valid ? (si * W + sj) : 0;   // w[k]==0 when invalid
        }
    }

    const int bbase = blockIdx.y * BPB + bg * BPW;
    float spv[BPW][9];
#pragma unroll
    for (int bb = 0; bb < BPW; ++bb) {
        const float* __restrict__ sp = spikes + (size_t)(bbase + bb) * S;
#pragma unroll
        for (int k = 0; k < 9; ++k)
            spv[bb][k] = sp[src[k]];
    }

    __syncthreads();                    // drains adj stores + spike loads

    // ---- Phase 3: apply ----
    float w[9];
#pragma unroll
    for (int k = 0; k < 9; ++k)
        w[k] = wsm[tL * 9 + k];         // stride-9: all banks, 2 lanes/bank

#pragma unroll
    for (int bb = 0; bb < BPW; ++bb) {
        float acc = 0.0f;
#pragma unroll
        for (int k = 0; k < 9; ++k)
            acc = fmaf(w[k], spv[bb][k], acc);
        out[(size_t)(bbase + bb) * S + t] = acc;
    }
}

extern "C" void kernel_launch(void* const* d_in, const int* in_sizes, int n_in,
                              void* d_out, int out_size, void* d_ws, size_t ws_size,
                              hipStream_t stream) {
    const float* spikes = (const float*)d_in[0];   // [32,128,128] f32
    const float* E      = (const float*)d_in[1];   // [128,128]    f32
    const float* adj    = (const float*)d_in[2];   // [16384,16384] f32
    float* out          = (float*)d_out;           // [32,128,128] f32

    dim3 block(TPB);
    dim3 grid(S / TGT_PER_BLK, YGRID);             // (256, 4) = 1024 blocks
    AxonalConnections_22608707846341_kernel<<<grid, block, 0, stream>>>(
        spikes, E, adj, out);
}